// Round 9
// baseline (709.481 us; speedup 1.0000x reference)
//
#include <hip/hip_runtime.h>
#include <hip/hip_bf16.h>

// CodeformerLM — round 9: logits GEMM -> direct-global MFMA (no LDS/barriers;
// operands L2-resident). Rest identical to round 8.

typedef __hip_bfloat16 bf16;
typedef __attribute__((ext_vector_type(8))) short short8;
typedef __attribute__((ext_vector_type(4))) float f32x4;

__device__ inline float b2f(bf16 x) { return __bfloat162float(x); }
__device__ inline bf16 f2b(float x) { return __float2bfloat16(x); }
__device__ inline short f2bs(float x) { bf16 h = __float2bfloat16(x); return *reinterpret_cast<short*>(&h); }
__device__ inline float gelu_f(float x) {
    return 0.5f * x * (1.f + tanhf(0.7978845608028654f * (x + 0.044715f * x * x * x)));
}
__device__ __forceinline__ void gload16(const void* g, void* l) {
    __builtin_amdgcn_global_load_lds(
        (const __attribute__((address_space(1))) unsigned int*)g,
        (__attribute__((address_space(3))) unsigned int*)l, 16, 0, 0);
}

// ---------------- batched weight transpose+convert: W[K][N] f32 -> Wt[N][K] bf16 ----------------
#define NMAT 26
struct TAll {
    const float* src[NMAT];
    bf16* dst[NMAT];
    int K[NMAT], N[NMAT];
    int ofs[NMAT + 1];
};

__global__ __launch_bounds__(256) void k_transpose(TAll ta) {
    __shared__ float tile[32][33];
    int bid = blockIdx.x;
    int m = 0;
    while (m + 1 < NMAT && bid >= ta.ofs[m + 1]) ++m;
    int local = bid - ta.ofs[m];
    int K = ta.K[m], N = ta.N[m];
    int tilesX = N >> 5;
    int tx = local % tilesX, ty = local / tilesX;
    int k0 = ty << 5, n0 = tx << 5;
    const float* src = ta.src[m];
    bf16* dst = ta.dst[m];
    int t = threadIdx.x;
    int c = t & 31, r = t >> 5;
#pragma unroll
    for (int p = 0; p < 4; ++p)
        tile[r + p * 8][c] = src[(long)(k0 + r + p * 8) * N + n0 + c];
    __syncthreads();
#pragma unroll
    for (int p = 0; p < 4; ++p)
        dst[(long)(n0 + r + p * 8) * K + k0 + c] = __float2bfloat16(tile[c][r + p * 8]);
}

// ---------------- direct-global MFMA GEMM (logits): no LDS, no barriers ----------------
// C[M][N] = A[M][K] @ Bt[N][K]^T + bias, f32 out. Operands L2-resident.
// Block = 2x2 waves, wave tile 64x64 (FM=FN=4: 8 loads -> 16 MFMAs per K-step).
// XCD co-location: grid (16, 256); all 16 m-tiles of an n-tile on one XCD.
__global__ __launch_bounds__(256) void k_gemm_direct(const bf16* __restrict__ A,
        const bf16* __restrict__ Bt, const float* __restrict__ bias,
        float* __restrict__ Cc, int M, int N, int K) {
    int pI = blockIdx.y * 16 + blockIdx.x;
    int q = pI >> 7, r = pI & 127;
    int mt = r >> 3, nt = q * 8 + (r & 7);
    if (nt * 128 >= N) return;               // no barriers -> early return safe
    int tid = threadIdx.x;
    int w = tid >> 6, l = tid & 63;
    int wm = w >> 1, wn = w & 1;
    int l16 = l & 15, kg = l >> 4;
    int m0 = mt * 128 + wm * 64, n0 = nt * 128 + wn * 64;
    const char* Ab = (const char*)A + ((long)(m0 + l16) * K + kg * 8) * 2;
    const char* Bb = (const char*)Bt + ((long)(n0 + l16) * K + kg * 8) * 2;
    long rstep = (long)16 * K * 2;           // 16 rows
    f32x4 acc[4][4];
#pragma unroll
    for (int i = 0; i < 4; ++i)
#pragma unroll
        for (int j = 0; j < 4; ++j) acc[i][j] = 0.f;

    int NS = K >> 5;                          // K-steps of 32
#pragma unroll 4
    for (int ks = 0; ks < NS; ++ks) {
        short8 a[4], b[4];
#pragma unroll
        for (int i = 0; i < 4; ++i)
            a[i] = *reinterpret_cast<const short8*>(Ab + i * rstep + ks * 64);
#pragma unroll
        for (int j = 0; j < 4; ++j)
            b[j] = *reinterpret_cast<const short8*>(Bb + j * rstep + ks * 64);
#pragma unroll
        for (int i = 0; i < 4; ++i)
#pragma unroll
            for (int j = 0; j < 4; ++j)
                acc[i][j] = __builtin_amdgcn_mfma_f32_16x16x32_bf16(a[i], b[j], acc[i][j], 0, 0, 0);
    }
#pragma unroll
    for (int i = 0; i < 4; ++i) {
#pragma unroll
        for (int jj = 0; jj < 4; ++jj) {
            int row = m0 + i * 16 + kg * 4 + jj;
            if (row < M) {
#pragma unroll
                for (int j = 0; j < 4; ++j) {
                    int col = n0 + j * 16 + l16;
                    Cc[(long)row * N + col] = acc[i][j][jj] + bias[col];
                }
            }
        }
    }
}

// ---------------- MFMA GEMM (dbuf prefetch, counted vmcnt, raw barriers) ----------------
template<int BM, int BN, int ACT, int BIAS, int OUTBF, int VT = 0>
__global__ __launch_bounds__(256) void k_gemm_mfma(const bf16* __restrict__ A,
        const bf16* __restrict__ Bt, const float* __restrict__ bias,
        void* __restrict__ Cc, int M, int N, int K, bf16* __restrict__ vt, int S) {
    constexpr int WM = BM / 2, WN = BN / 2, FM = WM / 16, FN = WN / 16;
    constexpr int L = BM / 32 + BN / 32;
    constexpr int ASZ = BM * 64, BSZ = BN * 64;
    __shared__ __align__(16) short As[2 * ASZ];
    __shared__ __align__(16) short Bs[2 * BSZ];
    int m0 = blockIdx.y * BM, n0 = blockIdx.x * BN;
    int tid = threadIdx.x;
    int w = tid >> 6, l = tid & 63;
    int wm = w >> 1, wn = w & 1;
    int l16 = l & 15, kg = l >> 4;
    int srow = l >> 3, scol = (l & 7) * 16;
    f32x4 acc[FM][FN];
#pragma unroll
    for (int i = 0; i < FM; ++i)
#pragma unroll
        for (int j = 0; j < FN; ++j) acc[i][j] = 0.f;

    auto stage = [&](int kt, int half) {
        long kof = (long)kt * 64;
#pragma unroll
        for (int p = 0; p < BM / 32; ++p) {
            int r = p * 32 + w * 8 + srow;
            gload16((const char*)A + (((long)(m0 + r) * K + kof) << 1) + (scol ^ ((r & 7) << 4)),
                    (char*)As + half * (ASZ * 2) + (p * 32 + w * 8) * 128);
        }
#pragma unroll
        for (int p = 0; p < BN / 32; ++p) {
            int r = p * 32 + w * 8 + srow;
            gload16((const char*)Bt + (((long)(n0 + r) * K + kof) << 1) + (scol ^ ((r & 7) << 4)),
                    (char*)Bs + half * (BSZ * 2) + (p * 32 + w * 8) * 128);
        }
    };

    int NT = K >> 6;
    stage(0, 0);
    for (int t = 0; t < NT; ++t) {
        int cur = t & 1;
        if (t + 1 < NT) {
            stage(t + 1, cur ^ 1);
            if constexpr (L == 3)      asm volatile("s_waitcnt vmcnt(3)" ::: "memory");
            else if constexpr (L == 4) asm volatile("s_waitcnt vmcnt(4)" ::: "memory");
            else if constexpr (L == 6) asm volatile("s_waitcnt vmcnt(6)" ::: "memory");
            else                       asm volatile("s_waitcnt vmcnt(8)" ::: "memory");
        } else {
            asm volatile("s_waitcnt vmcnt(0)" ::: "memory");
        }
        __builtin_amdgcn_s_barrier();
        const char* Ab = (const char*)As + cur * (ASZ * 2);
        const char* Bb = (const char*)Bs + cur * (BSZ * 2);
#pragma unroll
        for (int ks = 0; ks < 2; ++ks) {
            short8 a[FM], b[FN];
#pragma unroll
            for (int i = 0; i < FM; ++i) {
                int ar = wm * WM + i * 16 + l16;
                a[i] = *reinterpret_cast<const short8*>(Ab + ar * 128 + ((ks * 64 + kg * 16) ^ ((ar & 7) << 4)));
            }
#pragma unroll
            for (int j = 0; j < FN; ++j) {
                int br = wn * WN + j * 16 + l16;
                b[j] = *reinterpret_cast<const short8*>(Bb + br * 128 + ((ks * 64 + kg * 16) ^ ((br & 7) << 4)));
            }
#pragma unroll
            for (int i = 0; i < FM; ++i)
#pragma unroll
                for (int j = 0; j < FN; ++j)
                    acc[i][j] = __builtin_amdgcn_mfma_f32_16x16x32_bf16(a[i], b[j], acc[i][j], 0, 0, 0);
        }
        asm volatile("s_waitcnt lgkmcnt(0)" ::: "memory");
        __builtin_amdgcn_sched_barrier(0);
        __builtin_amdgcn_s_barrier();
    }
#pragma unroll
    for (int i = 0; i < FM; ++i) {
#pragma unroll
        for (int jj = 0; jj < 4; ++jj) {
            int row = m0 + wm * WM + i * 16 + kg * 4 + jj;
            if (row < M) {
#pragma unroll
                for (int j = 0; j < FN; ++j) {
                    int col = n0 + wn * WN + j * 16 + l16;
                    float v = acc[i][j][jj];
                    if (BIAS) v += bias[col];
                    if (ACT) v = gelu_f(v);
                    if (VT && col >= 1024) {
                        int hh = (col - 1024) >> 6, dd = (col - 1024) & 63;
                        int sq = row / S, key = row - sq * S;
                        int SPl = ((S + 31) >> 5) << 5;
                        vt[(((long)sq * 8 + hh) * 64 + dd) * SPl + key] = f2b(v);
                    } else if (OUTBF) {
                        ((bf16*)Cc)[(long)row * N + col] = f2b(v);
                    } else {
                        ((float*)Cc)[(long)row * N + col] = v;
                    }
                }
            }
        }
    }
}

// ---------------- barrier-free MFMA attention: 1 wave per (seq, head, q-tile) ----------------
template<int S>
__global__ __launch_bounds__(64) void k_attn_mfma(const bf16* __restrict__ qkv,
        const bf16* __restrict__ vt, bf16* __restrict__ att,
        const int* __restrict__ limits, int causal) {
    constexpr int KT = S / 16;
    constexpr int SP = ((S + 31) / 32) * 32;
    constexpr int KS = SP / 32;
    constexpr int SPAD = SP - KT * 16;
    __shared__ __align__(16) short Pw[16 * 104];
    int bid = blockIdx.x;
    int qt = bid % KT;
    int bh = bid / KT;
    int h = bh & 7, seq = bh >> 3;
    int l = threadIdx.x;
    int l16 = l & 15, kg = l >> 4;
    int lim = limits ? limits[seq] : S;
    const short* qk = (const short*)qkv + (long)seq * S * 1536 + h * 64;
    const short* vb_base = (const short*)vt + ((long)(seq * 8 + h) * 64) * SP;

    f32x4 sc[KT];
#pragma unroll
    for (int kt = 0; kt < KT; ++kt) sc[kt] = 0.f;
#pragma unroll
    for (int ks = 0; ks < 2; ++ks) {
        short8 qa = *reinterpret_cast<const short8*>(qk + (long)(qt * 16 + l16) * 1536 + ks * 32 + kg * 8);
#pragma unroll
        for (int kt = 0; kt < KT; ++kt) {
            short8 kb = *reinterpret_cast<const short8*>(qk + (long)(kt * 16 + l16) * 1536 + 512 + ks * 32 + kg * 8);
            sc[kt] = __builtin_amdgcn_mfma_f32_16x16x32_bf16(qa, kb, sc[kt], 0, 0, 0);
        }
    }
#pragma unroll
    for (int jj = 0; jj < 4; ++jj) {
        int q = qt * 16 + kg * 4 + jj;
        float vs[KT], m = -1e30f;
#pragma unroll
        for (int kt = 0; kt < KT; ++kt) {
            int key = kt * 16 + l16;
            float s = sc[kt][jj] * 0.125f;
            bool ok = (!causal || key <= q) && (key < lim);
            vs[kt] = ok ? s : -1e30f;
            m = fmaxf(m, vs[kt]);
        }
#pragma unroll
        for (int o = 1; o < 16; o <<= 1) m = fmaxf(m, __shfl_xor(m, o));
        float sum = 0.f;
#pragma unroll
        for (int kt = 0; kt < KT; ++kt) { vs[kt] = __expf(vs[kt] - m); sum += vs[kt]; }
#pragma unroll
        for (int o = 1; o < 16; o <<= 1) sum += __shfl_xor(sum, o);
        float rinv = 1.f / sum;
#pragma unroll
        for (int kt = 0; kt < KT; ++kt)
            Pw[(kg * 4 + jj) * 104 + kt * 16 + l16] = f2bs(vs[kt] * rinv);
    }
    if (SPAD > 0) {
#pragma unroll
        for (int jj = 0; jj < 4; ++jj)
            Pw[(kg * 4 + jj) * 104 + KT * 16 + l16] = 0;
    }
    f32x4 ao[4];
#pragma unroll
    for (int ct = 0; ct < 4; ++ct) ao[ct] = 0.f;
#pragma unroll
    for (int kst = 0; kst < KS; ++kst) {
        short8 pa = *reinterpret_cast<const short8*>((const char*)Pw + l16 * 208 + kst * 64 + kg * 16);
#pragma unroll
        for (int ct = 0; ct < 4; ++ct) {
            short8 vbf = *reinterpret_cast<const short8*>(vb_base + (long)(ct * 16 + l16) * SP + kst * 32 + kg * 8);
            ao[ct] = __builtin_amdgcn_mfma_f32_16x16x32_bf16(pa, vbf, ao[ct], 0, 0, 0);
        }
    }
#pragma unroll
    for (int ct = 0; ct < 4; ++ct)
#pragma unroll
        for (int jj = 0; jj < 4; ++jj) {
            int q = qt * 16 + kg * 4 + jj;
            att[((long)seq * S + q) * 512 + h * 64 + ct * 16 + l16] = f2b(ao[ct][jj]);
        }
}

// ---------------- LayerNorm helpers ----------------
__device__ inline void ln_finish(float v0, float v1, const float* __restrict__ lnw,
                                 bf16* __restrict__ outrow) {
    float s = v0 + v1, q = v0 * v0 + v1 * v1;
#pragma unroll
    for (int o = 32; o > 0; o >>= 1) { s += __shfl_xor(s, o); q += __shfl_xor(q, o); }
    __shared__ float rs[4], rq[4];
    int w = threadIdx.x >> 6;
    if ((threadIdx.x & 63) == 0) { rs[w] = s; rq[w] = q; }
    __syncthreads();
    s = rs[0] + rs[1] + rs[2] + rs[3];
    q = rq[0] + rq[1] + rq[2] + rq[3];
    float m = s * (1.f / 512.f);
    float var = q * (1.f / 512.f) - m * m;
    float inv = rsqrtf(var + 1e-7f);
    int i0 = threadIdx.x * 2, i1 = i0 + 1;
    outrow[i0] = f2b((v0 - m) * inv * lnw[i0] + lnw[512 + i0]);
    outrow[i1] = f2b((v1 - m) * inv * lnw[i1] + lnw[512 + i1]);
}

__global__ __launch_bounds__(256) void k_embed_ln2(const int* __restrict__ ids,
        const float* __restrict__ tok_emb, const float* __restrict__ tok_lnw,
        const float* __restrict__ dec_emb, const float* __restrict__ dec_lnw,
        bf16* __restrict__ x, bf16* __restrict__ dec_tok) {
    int row = blockIdx.x;
    const float* emb; const float* lnw; bf16* out;
    if (row < 2048) { emb = tok_emb; lnw = tok_lnw; out = x + (long)row * 512; }
    else { row -= 2048; emb = dec_emb; lnw = dec_lnw; out = dec_tok + (long)row * 512; }
    const float* e = emb + (long)ids[row] * 512;
    int i0 = threadIdx.x * 2;
    ln_finish(e[i0], e[i0 + 1], lnw, out);
}

__global__ __launch_bounds__(256) void k_add_ln(const bf16* __restrict__ a, const bf16* __restrict__ b,
        const float* __restrict__ lnw, bf16* __restrict__ out) {
    int row = blockIdx.x;
    long off = (long)row * 512;
    int i0 = threadIdx.x * 2;
    float v0 = b2f(a[off + i0]), v1 = b2f(a[off + i0 + 1]);
    if (b) { v0 += b2f(b[off + i0]); v1 += b2f(b[off + i0 + 1]); }
    ln_finish(v0, v1, lnw, out + off);
}

__global__ __launch_bounds__(256) void k_chunk_ln(const bf16* __restrict__ tu, const float* __restrict__ cpos,
        const float* __restrict__ lnw, bf16* __restrict__ out) {
    int bc = blockIdx.x;
    int c = bc & 15;
    long toff = (long)bc * 64 * 512;
    int i0 = threadIdx.x * 2;
    float v0 = b2f(tu[toff + i0])     + cpos[c * 512 + i0];
    float v1 = b2f(tu[toff + i0 + 1]) + cpos[c * 512 + i0 + 1];
    ln_finish(v0, v1, lnw, out + (long)bc * 512);
}

// ---------------- Decoder-input build ----------------
__global__ __launch_bounds__(256) void k_dec_in(const bf16* __restrict__ chunk_units,
        const float* __restrict__ sos, const bf16* __restrict__ dec_tok,
        const int* __restrict__ num_chunks, const int* __restrict__ num_tokens,
        bf16* __restrict__ out) {
    int row = blockIdx.x;
    int p = row % 80;
    int bc = row / 80;
    int c = bc & 15, b = bc >> 4;
    int t = threadIdx.x;
    bf16* o = out + (long)row * 512;
    if (c < num_chunks[b]) {
        if (p <= c) {
            if (p == 0) {
                o[2 * t]     = f2b(sos[2 * t]);
                o[2 * t + 1] = f2b(sos[2 * t + 1]);
                return;
            }
            ((uint*)o)[t] = ((const uint*)(chunk_units + ((long)(b * 16 + p - 1)) * 512))[t];
            return;
        }
        int n = num_tokens[bc];
        if (p <= c + n) {
            ((uint*)o)[t] = ((const uint*)(dec_tok + ((long)bc * 64 + (p - c - 1)) * 512))[t];
            return;
        }
    }
    ((uint*)o)[t] = 0u;
}

// ---------------- Head gather ----------------
__global__ __launch_bounds__(256) void k_head_gather(const bf16* __restrict__ units,
        const int* __restrict__ num_chunks, const int* __restrict__ num_tokens,
        bf16* __restrict__ out) {
    int row = blockIdx.x;
    int t = row % 63;
    int bc = row / 63;
    int c = bc & 15, b = bc >> 4;
    bool valid = (c < num_chunks[b]) && (t < num_tokens[bc] - 1);
    uint* o = (uint*)(out + (long)row * 512);
    if (valid) {
        o[threadIdx.x] = ((const uint*)(units + ((long)bc * 80 + (c + 1 + t)) * 512))[threadIdx.x];
    } else {
        o[threadIdx.x] = 0u;
    }
}

// ---------------- Encoder driver (L=2 layers) ----------------
template<int S>
static void run_encoder(hipStream_t st, bf16* x, int nseq, const int* limits, int causal,
                        bf16* const* wts, const float* ln1, const float* ln2,
                        bf16* qkv, bf16* vt, bf16* att, bf16* proj, bf16* x2, bf16* h1) {
    constexpr int KT = S / 16;
    int R = nseq * S;
    int gy64 = (R + 63) / 64, gy32 = (R + 31) / 32;
    for (int l = 0; l < 2; ++l) {
        k_gemm_mfma<64, 64, 0, 0, 1, 1><<<dim3(24, gy64), 256, 0, st>>>(x, wts[l * 4 + 0], nullptr, qkv, R, 1536, 512, vt, S);
        k_attn_mfma<S><<<dim3(nseq * 8 * KT), 64, 0, st>>>(qkv, vt, att, limits, causal);
        k_gemm_mfma<32, 64, 0, 0, 1><<<dim3(8, gy32), 256, 0, st>>>(att, wts[l * 4 + 1], nullptr, proj, R, 512, 512, nullptr, 0);
        k_add_ln<<<dim3(R), 256, 0, st>>>(x, proj, ln1 + (long)l * 1024, x2);
        k_gemm_mfma<64, 64, 1, 0, 1><<<dim3(32, gy64), 256, 0, st>>>(x2, wts[l * 4 + 2], nullptr, h1, R, 2048, 512, nullptr, 0);
        k_gemm_mfma<32, 64, 0, 0, 1><<<dim3(8, gy32), 256, 0, st>>>(h1, wts[l * 4 + 3], nullptr, proj, R, 512, 2048, nullptr, 0);
        k_add_ln<<<dim3(R), 256, 0, st>>>(x2, proj, ln2 + (long)l * 1024, x);
    }
}

extern "C" void kernel_launch(void* const* d_in, const int* in_sizes, int n_in,
                              void* d_out, int out_size, void* d_ws, size_t ws_size,
                              hipStream_t stream) {
    (void)in_sizes; (void)n_in; (void)out_size; (void)ws_size;
    const int*   token_ids    = (const int*)d_in[0];
    const int*   num_chunks   = (const int*)d_in[1];
    const int*   num_tokens   = (const int*)d_in[2];
    const float* tok_emb      = (const float*)d_in[3];
    const float* tok_emb_ln   = (const float*)d_in[4];
    const float* chunk_pos    = (const float*)d_in[5];
    const float* chunk_emb_ln = (const float*)d_in[6];
    const float* sos          = (const float*)d_in[7];
    const float* dec_emb      = (const float*)d_in[8];
    const float* dec_emb_ln   = (const float*)d_in[9];
    const float* cls_dense    = (const float*)d_in[10];
    const float* cls_ln       = (const float*)d_in[11];
    const float* cls_proj     = (const float*)d_in[12];
    const float* cls_b        = (const float*)d_in[13];
    const float* w_in[3][4] = {
        {(const float*)d_in[14], (const float*)d_in[15], (const float*)d_in[17], (const float*)d_in[18]},
        {(const float*)d_in[20], (const float*)d_in[21], (const float*)d_in[23], (const float*)d_in[24]},
        {(const float*)d_in[26], (const float*)d_in[27], (const float*)d_in[29], (const float*)d_in[30]},
    };
    const float* ln_in[3][2] = {
        {(const float*)d_in[16], (const float*)d_in[19]},
        {(const float*)d_in[22], (const float*)d_in[25]},
        {(const float*)d_in[28], (const float*)d_in[31]},
    };

    char* p = (char*)d_ws;
    auto carve_b = [&](size_t elems) {
        bf16* r = (bf16*)p;
        p += ((elems * 2 + 255) / 256) * 256;
        return r;
    };
    bf16* x       = carve_b((size_t)2560 * 512);
    bf16* qkv     = carve_b((size_t)2560 * 1536);
    bf16* vt      = carve_b((size_t)32 * 8 * 64 * 96);
    bf16* att     = carve_b((size_t)2560 * 512);
    bf16* proj    = carve_b((size_t)2560 * 512);
    bf16* x2      = carve_b((size_t)2560 * 512);
    bf16* h1      = carve_b((size_t)2560 * 2048);
    bf16* chunk_x = carve_b((size_t)64 * 512);
    bf16* dec_tok = carve_b((size_t)2048 * 512);
    bf16* unitsre = carve_b((size_t)2048 * 512);
    bf16* hbuf    = carve_b((size_t)2048 * 512);
    bf16* ybuf    = carve_b((size_t)2048 * 512);

    TAll ta;
    int nm = 0, tiles = 0;
    auto push = [&](const float* src, int K, int N) -> bf16* {
        bf16* dst = carve_b((size_t)K * N);
        ta.src[nm] = src; ta.dst[nm] = dst; ta.K[nm] = K; ta.N[nm] = N;
        ta.ofs[nm] = tiles;
        tiles += (K / 32) * (N / 32);
        ++nm;
        return dst;
    };
    static const int KN[4][2] = {{512, 1536}, {512, 512}, {512, 2048}, {2048, 512}};
    bf16* wt[3][8];
    for (int tf = 0; tf < 3; ++tf)
        for (int l = 0; l < 2; ++l)
            for (int m = 0; m < 4; ++m) {
                int K = KN[m][0], N = KN[m][1];
                wt[tf][l * 4 + m] = push(w_in[tf][m] + (long)l * K * N, K, N);
            }
    bf16* wt_dense = push(cls_dense, 512, 512);
    bf16* wt_proj  = push(cls_proj, 512, 32000);
    ta.ofs[nm] = tiles;   // nm == NMAT == 26

    k_transpose<<<dim3(tiles), 256, 0, stream>>>(ta);

    // embeddings (tok + dec merged)
    k_embed_ln2<<<4096, 256, 0, stream>>>(token_ids, tok_emb, tok_emb_ln, dec_emb, dec_emb_ln, x, dec_tok);

    // 1) token encoder (32 seq x 64)
    run_encoder<64>(stream, x, 32, num_tokens, 0, wt[0], ln_in[0][0], ln_in[0][1],
                    qkv, vt, att, proj, x2, h1);
    // 2) chunk encoder (2 seq x 16)
    k_chunk_ln<<<32, 256, 0, stream>>>(x, chunk_pos, chunk_emb_ln, chunk_x);
    run_encoder<16>(stream, chunk_x, 2, num_chunks, 1, wt[1], ln_in[1][0], ln_in[1][1],
                    qkv, vt, att, proj, x2, h1);
    // 3) decoder (32 seq x 80)
    k_dec_in<<<2560, 256, 0, stream>>>(chunk_x, sos, dec_tok, num_chunks, num_tokens, x);
    run_encoder<80>(stream, x, 32, nullptr, 1, wt[2], ln_in[2][0], ln_in[2][1],
                    qkv, vt, att, proj, x2, h1);
    // 4) head
    k_head_gather<<<2016, 256, 0, stream>>>(x, num_chunks, num_tokens, unitsre);
    k_gemm_mfma<32, 64, 1, 0, 1><<<dim3(8, 63), 256, 0, stream>>>(unitsre, wt_dense, nullptr, hbuf, 2016, 512, 512, nullptr, 0);
    k_add_ln<<<2016, 256, 0, stream>>>(hbuf, nullptr, cls_ln, ybuf);
    // logits: direct-global MFMA, 128x128 blocks, XCD co-location (16 m-tiles x 250 n-tiles)
    k_gemm_direct<<<dim3(16, 256), 256, 0, stream>>>(ybuf, wt_proj, cls_b, (float*)d_out, 2016, 32000, 512);
}

// Round 10
// 499.773 us; speedup vs baseline: 1.4196x; 1.4196x over previous
//
#include <hip/hip_runtime.h>
#include <hip/hip_bf16.h>

// CodeformerLM — round 10: coalesced epilogues. Logits GEMM: LDS-transpose ->
// 512B f32 segment stores. qkv VT path: LDS-transpose -> 128B packed bf16 stores.
// K-loop structure identical to round 7/8 (staged gload_lds, dbuf, counted vmcnt).

typedef __hip_bfloat16 bf16;
typedef __attribute__((ext_vector_type(8))) short short8;
typedef __attribute__((ext_vector_type(4))) float f32x4;

__device__ inline float b2f(bf16 x) { return __bfloat162float(x); }
__device__ inline bf16 f2b(float x) { return __float2bfloat16(x); }
__device__ inline short f2bs(float x) { bf16 h = __float2bfloat16(x); return *reinterpret_cast<short*>(&h); }
__device__ inline float gelu_f(float x) {
    return 0.5f * x * (1.f + tanhf(0.7978845608028654f * (x + 0.044715f * x * x * x)));
}
__device__ __forceinline__ void gload16(const void* g, void* l) {
    __builtin_amdgcn_global_load_lds(
        (const __attribute__((address_space(1))) unsigned int*)g,
        (__attribute__((address_space(3))) unsigned int*)l, 16, 0, 0);
}

// ---------------- batched weight transpose+convert: W[K][N] f32 -> Wt[N][K] bf16 ----------------
#define NMAT 26
struct TAll {
    const float* src[NMAT];
    bf16* dst[NMAT];
    int K[NMAT], N[NMAT];
    int ofs[NMAT + 1];
};

__global__ __launch_bounds__(256) void k_transpose(TAll ta) {
    __shared__ float tile[32][33];
    int bid = blockIdx.x;
    int m = 0;
    while (m + 1 < NMAT && bid >= ta.ofs[m + 1]) ++m;
    int local = bid - ta.ofs[m];
    int K = ta.K[m], N = ta.N[m];
    int tilesX = N >> 5;
    int tx = local % tilesX, ty = local / tilesX;
    int k0 = ty << 5, n0 = tx << 5;
    const float* src = ta.src[m];
    bf16* dst = ta.dst[m];
    int t = threadIdx.x;
    int c = t & 31, r = t >> 5;
#pragma unroll
    for (int p = 0; p < 4; ++p)
        tile[r + p * 8][c] = src[(long)(k0 + r + p * 8) * N + n0 + c];
    __syncthreads();
#pragma unroll
    for (int p = 0; p < 4; ++p)
        dst[(long)(n0 + r + p * 8) * K + k0 + c] = __float2bfloat16(tile[c][r + p * 8]);
}

// ---------------- MFMA GEMM (dbuf prefetch, counted vmcnt, raw barriers) ----------------
// C[M][N] = act(A[M][K] @ Bt[N][K]^T (+bias)). XOR swizzle both sides.
// VT: n0>=1024 blocks (V third of qkv) -> LDS-transposed coalesced write to vt.
// SWZ: XCD co-location remap. EPIF32: LDS-transposed coalesced f32 stores (BN=128).
template<int BM, int BN, int ACT, int BIAS, int OUTBF, int VT = 0, int SWZ = 0, int EPIF32 = 0>
__global__ __launch_bounds__(256) void k_gemm_mfma(const bf16* __restrict__ A,
        const bf16* __restrict__ Bt, const float* __restrict__ bias,
        void* __restrict__ Cc, int M, int N, int K, bf16* __restrict__ vt, int S) {
    constexpr int WM = BM / 2, WN = BN / 2, FM = WM / 16, FN = WN / 16;
    constexpr int L = BM / 32 + BN / 32;
    constexpr int ASZ = BM * 64, BSZ = BN * 64;           // shorts per half-buffer
    constexpr int SB = (ASZ + BSZ) * 2 * 2;               // stage bytes (dbuf)
    constexpr int EBf = EPIF32 ? BM * (BN + 4) * 4 : 0;   // f32 transpose tile
    constexpr int EBv = VT ? 64 * 69 * 4 : 0;
    constexpr int SMEM = SB > EBf ? (SB > EBv ? SB : EBv) : (EBf > EBv ? EBf : EBv);
    __shared__ __align__(16) char smem[SMEM];
    short* As = (short*)smem;
    short* Bs = (short*)smem + 2 * ASZ;

    int m0, n0;
    if constexpr (SWZ) {
        int pI = blockIdx.y * 16 + blockIdx.x;
        int q = pI >> 7, r = pI & 127;
        int mt = r >> 3, nt = q * 8 + (r & 7);
        if (nt * BN >= N) return;      // whole-block early exit (before any barrier)
        m0 = mt * BM; n0 = nt * BN;
    } else {
        m0 = blockIdx.y * BM; n0 = blockIdx.x * BN;
    }
    int tid = threadIdx.x;
    int w = tid >> 6, l = tid & 63;
    int wm = w >> 1, wn = w & 1;
    int l16 = l & 15, kg = l >> 4;
    int srow = l >> 3, scol = (l & 7) * 16;
    f32x4 acc[FM][FN];
#pragma unroll
    for (int i = 0; i < FM; ++i)
#pragma unroll
        for (int j = 0; j < FN; ++j) acc[i][j] = 0.f;

    auto stage = [&](int kt, int half) {
        long kof = (long)kt * 64;
#pragma unroll
        for (int p = 0; p < BM / 32; ++p) {
            int r = p * 32 + w * 8 + srow;
            gload16((const char*)A + (((long)(m0 + r) * K + kof) << 1) + (scol ^ ((r & 7) << 4)),
                    (char*)As + half * (ASZ * 2) + (p * 32 + w * 8) * 128);
        }
#pragma unroll
        for (int p = 0; p < BN / 32; ++p) {
            int r = p * 32 + w * 8 + srow;
            gload16((const char*)Bt + (((long)(n0 + r) * K + kof) << 1) + (scol ^ ((r & 7) << 4)),
                    (char*)Bs + half * (BSZ * 2) + (p * 32 + w * 8) * 128);
        }
    };

    int NT = K >> 6;
    stage(0, 0);
    for (int t = 0; t < NT; ++t) {
        int cur = t & 1;
        if (t + 1 < NT) {
            stage(t + 1, cur ^ 1);
            if constexpr (L == 3)      asm volatile("s_waitcnt vmcnt(3)" ::: "memory");
            else if constexpr (L == 4) asm volatile("s_waitcnt vmcnt(4)" ::: "memory");
            else if constexpr (L == 6) asm volatile("s_waitcnt vmcnt(6)" ::: "memory");
            else                       asm volatile("s_waitcnt vmcnt(8)" ::: "memory");
        } else {
            asm volatile("s_waitcnt vmcnt(0)" ::: "memory");
        }
        __builtin_amdgcn_s_barrier();
        const char* Ab = (const char*)As + cur * (ASZ * 2);
        const char* Bb = (const char*)Bs + cur * (BSZ * 2);
#pragma unroll
        for (int ks = 0; ks < 2; ++ks) {
            short8 a[FM], b[FN];
#pragma unroll
            for (int i = 0; i < FM; ++i) {
                int ar = wm * WM + i * 16 + l16;
                a[i] = *reinterpret_cast<const short8*>(Ab + ar * 128 + ((ks * 64 + kg * 16) ^ ((ar & 7) << 4)));
            }
#pragma unroll
            for (int j = 0; j < FN; ++j) {
                int br = wn * WN + j * 16 + l16;
                b[j] = *reinterpret_cast<const short8*>(Bb + br * 128 + ((ks * 64 + kg * 16) ^ ((br & 7) << 4)));
            }
#pragma unroll
            for (int i = 0; i < FM; ++i)
#pragma unroll
                for (int j = 0; j < FN; ++j)
                    acc[i][j] = __builtin_amdgcn_mfma_f32_16x16x32_bf16(a[i], b[j], acc[i][j], 0, 0, 0);
        }
        asm volatile("s_waitcnt lgkmcnt(0)" ::: "memory");
        __builtin_amdgcn_sched_barrier(0);
        __builtin_amdgcn_s_barrier();
    }

    // ---- epilogue A: coalesced f32 (logits). D col=lane&15, row=(lane>>4)*4+reg ----
    if constexpr (EPIF32) {
        static_assert(BN == 128, "EPIF32 assumes BN=128");
        float* T = (float*)smem;
        constexpr int LDT = BN + 4;
#pragma unroll
        for (int i = 0; i < FM; ++i)
#pragma unroll
            for (int j = 0; j < FN; ++j)
#pragma unroll
                for (int jj = 0; jj < 4; ++jj)
                    T[(wm * WM + i * 16 + kg * 4 + jj) * LDT + wn * WN + j * 16 + l16] = acc[i][j][jj];
        __syncthreads();
#pragma unroll
        for (int it = 0; it < BM / 8; ++it) {
            int rr = w * (BM / 4) + it * 2 + (l >> 5);
            int row = m0 + rr;
            int col = (l & 31) * 4;
            float4 v = *reinterpret_cast<const float4*>(&T[rr * LDT + col]);
            if (BIAS) {
                float4 bb = *reinterpret_cast<const float4*>(&bias[n0 + col]);
                v.x += bb.x; v.y += bb.y; v.z += bb.z; v.w += bb.w;
            }
            if (row < M)
                *reinterpret_cast<float4*>(&((float*)Cc)[(long)row * N + n0 + col]) = v;
        }
        return;
    }
    // ---- epilogue B: V-transpose blocks of qkv (coalesced vt writes) ----
    if constexpr (VT) {
        if (n0 >= 1024) {
            float* T = (float*)smem;           // [64 keys][69] f32
#pragma unroll
            for (int i = 0; i < FM; ++i)
#pragma unroll
                for (int j = 0; j < FN; ++j)
#pragma unroll
                    for (int jj = 0; jj < 4; ++jj)
                        T[(wm * WM + i * 16 + kg * 4 + jj) * 69 + wn * WN + j * 16 + l16] = acc[i][j][jj];
            __syncthreads();
            int h = (n0 - 1024) >> 6;
            int SPl = ((S + 31) >> 5) << 5;
#pragma unroll
            for (int it = 0; it < 8; ++it) {   // 64 d-rows / 4 waves, 2 rows per instr
                int d = w * 16 + it * 2 + (l >> 5);
                int lr = (l & 31) * 2;
                int g = m0 + lr;
                int sq = g / S, key = g - sq * S;   // pairs never straddle seq boundary (even)
                uint pk = (uint)(unsigned short)f2bs(T[lr * 69 + d]) |
                          ((uint)(unsigned short)f2bs(T[(lr + 1) * 69 + d]) << 16);
                *reinterpret_cast<uint*>(vt + (((long)(sq * 8 + h) * 64 + d) * SPl + key)) = pk;
            }
            return;
        }
    }
    // ---- epilogue C: scalar (encoder GEMMs, bf16/f32) ----
#pragma unroll
    for (int i = 0; i < FM; ++i) {
#pragma unroll
        for (int jj = 0; jj < 4; ++jj) {
            int row = m0 + wm * WM + i * 16 + kg * 4 + jj;
            if (row < M) {
#pragma unroll
                for (int j = 0; j < FN; ++j) {
                    int col = n0 + wn * WN + j * 16 + l16;
                    float v = acc[i][j][jj];
                    if (BIAS) v += bias[col];
                    if (ACT) v = gelu_f(v);
                    if (OUTBF) ((bf16*)Cc)[(long)row * N + col] = f2b(v);
                    else       ((float*)Cc)[(long)row * N + col] = v;
                }
            }
        }
    }
}

// ---------------- barrier-free MFMA attention: 1 wave per (seq, head, q-tile) ----------------
template<int S>
__global__ __launch_bounds__(64) void k_attn_mfma(const bf16* __restrict__ qkv,
        const bf16* __restrict__ vt, bf16* __restrict__ att,
        const int* __restrict__ limits, int causal) {
    constexpr int KT = S / 16;
    constexpr int SP = ((S + 31) / 32) * 32;
    constexpr int KS = SP / 32;
    constexpr int SPAD = SP - KT * 16;
    __shared__ __align__(16) short Pw[16 * 104];
    int bid = blockIdx.x;
    int qt = bid % KT;
    int bh = bid / KT;
    int h = bh & 7, seq = bh >> 3;
    int l = threadIdx.x;
    int l16 = l & 15, kg = l >> 4;
    int lim = limits ? limits[seq] : S;
    const short* qk = (const short*)qkv + (long)seq * S * 1536 + h * 64;
    const short* vb_base = (const short*)vt + ((long)(seq * 8 + h) * 64) * SP;

    f32x4 sc[KT];
#pragma unroll
    for (int kt = 0; kt < KT; ++kt) sc[kt] = 0.f;
#pragma unroll
    for (int ks = 0; ks < 2; ++ks) {
        short8 qa = *reinterpret_cast<const short8*>(qk + (long)(qt * 16 + l16) * 1536 + ks * 32 + kg * 8);
#pragma unroll
        for (int kt = 0; kt < KT; ++kt) {
            short8 kb = *reinterpret_cast<const short8*>(qk + (long)(kt * 16 + l16) * 1536 + 512 + ks * 32 + kg * 8);
            sc[kt] = __builtin_amdgcn_mfma_f32_16x16x32_bf16(qa, kb, sc[kt], 0, 0, 0);
        }
    }
#pragma unroll
    for (int jj = 0; jj < 4; ++jj) {
        int q = qt * 16 + kg * 4 + jj;
        float vs[KT], m = -1e30f;
#pragma unroll
        for (int kt = 0; kt < KT; ++kt) {
            int key = kt * 16 + l16;
            float s = sc[kt][jj] * 0.125f;
            bool ok = (!causal || key <= q) && (key < lim);
            vs[kt] = ok ? s : -1e30f;
            m = fmaxf(m, vs[kt]);
        }
#pragma unroll
        for (int o = 1; o < 16; o <<= 1) m = fmaxf(m, __shfl_xor(m, o));
        float sum = 0.f;
#pragma unroll
        for (int kt = 0; kt < KT; ++kt) { vs[kt] = __expf(vs[kt] - m); sum += vs[kt]; }
#pragma unroll
        for (int o = 1; o < 16; o <<= 1) sum += __shfl_xor(sum, o);
        float rinv = 1.f / sum;
#pragma unroll
        for (int kt = 0; kt < KT; ++kt)
            Pw[(kg * 4 + jj) * 104 + kt * 16 + l16] = f2bs(vs[kt] * rinv);
    }
    if (SPAD > 0) {
#pragma unroll
        for (int jj = 0; jj < 4; ++jj)
            Pw[(kg * 4 + jj) * 104 + KT * 16 + l16] = 0;
    }
    f32x4 ao[4];
#pragma unroll
    for (int ct = 0; ct < 4; ++ct) ao[ct] = 0.f;
#pragma unroll
    for (int kst = 0; kst < KS; ++kst) {
        short8 pa = *reinterpret_cast<const short8*>((const char*)Pw + l16 * 208 + kst * 64 + kg * 16);
#pragma unroll
        for (int ct = 0; ct < 4; ++ct) {
            short8 vbf = *reinterpret_cast<const short8*>(vb_base + (long)(ct * 16 + l16) * SP + kst * 32 + kg * 8);
            ao[ct] = __builtin_amdgcn_mfma_f32_16x16x32_bf16(pa, vbf, ao[ct], 0, 0, 0);
        }
    }
#pragma unroll
    for (int ct = 0; ct < 4; ++ct)
#pragma unroll
        for (int jj = 0; jj < 4; ++jj) {
            int q = qt * 16 + kg * 4 + jj;
            att[((long)seq * S + q) * 512 + h * 64 + ct * 16 + l16] = f2b(ao[ct][jj]);
        }
}

// ---------------- LayerNorm helpers ----------------
__device__ inline void ln_finish(float v0, float v1, const float* __restrict__ lnw,
                                 bf16* __restrict__ outrow) {
    float s = v0 + v1, q = v0 * v0 + v1 * v1;
#pragma unroll
    for (int o = 32; o > 0; o >>= 1) { s += __shfl_xor(s, o); q += __shfl_xor(q, o); }
    __shared__ float rs[4], rq[4];
    int w = threadIdx.x >> 6;
    if ((threadIdx.x & 63) == 0) { rs[w] = s; rq[w] = q; }
    __syncthreads();
    s = rs[0] + rs[1] + rs[2] + rs[3];
    q = rq[0] + rq[1] + rq[2] + rq[3];
    float m = s * (1.f / 512.f);
    float var = q * (1.f / 512.f) - m * m;
    float inv = rsqrtf(var + 1e-7f);
    int i0 = threadIdx.x * 2, i1 = i0 + 1;
    outrow[i0] = f2b((v0 - m) * inv * lnw[i0] + lnw[512 + i0]);
    outrow[i1] = f2b((v1 - m) * inv * lnw[i1] + lnw[512 + i1]);
}

__global__ __launch_bounds__(256) void k_embed_ln2(const int* __restrict__ ids,
        const float* __restrict__ tok_emb, const float* __restrict__ tok_lnw,
        const float* __restrict__ dec_emb, const float* __restrict__ dec_lnw,
        bf16* __restrict__ x, bf16* __restrict__ dec_tok) {
    int row = blockIdx.x;
    const float* emb; const float* lnw; bf16* out;
    if (row < 2048) { emb = tok_emb; lnw = tok_lnw; out = x + (long)row * 512; }
    else { row -= 2048; emb = dec_emb; lnw = dec_lnw; out = dec_tok + (long)row * 512; }
    const float* e = emb + (long)ids[row] * 512;
    int i0 = threadIdx.x * 2;
    ln_finish(e[i0], e[i0 + 1], lnw, out);
}

__global__ __launch_bounds__(256) void k_add_ln(const bf16* __restrict__ a, const bf16* __restrict__ b,
        const float* __restrict__ lnw, bf16* __restrict__ out) {
    int row = blockIdx.x;
    long off = (long)row * 512;
    int i0 = threadIdx.x * 2;
    float v0 = b2f(a[off + i0]), v1 = b2f(a[off + i0 + 1]);
    if (b) { v0 += b2f(b[off + i0]); v1 += b2f(b[off + i0 + 1]); }
    ln_finish(v0, v1, lnw, out + off);
}

__global__ __launch_bounds__(256) void k_chunk_ln(const bf16* __restrict__ tu, const float* __restrict__ cpos,
        const float* __restrict__ lnw, bf16* __restrict__ out) {
    int bc = blockIdx.x;
    int c = bc & 15;
    long toff = (long)bc * 64 * 512;
    int i0 = threadIdx.x * 2;
    float v0 = b2f(tu[toff + i0])     + cpos[c * 512 + i0];
    float v1 = b2f(tu[toff + i0 + 1]) + cpos[c * 512 + i0 + 1];
    ln_finish(v0, v1, lnw, out + (long)bc * 512);
}

// ---------------- Decoder-input build ----------------
__global__ __launch_bounds__(256) void k_dec_in(const bf16* __restrict__ chunk_units,
        const float* __restrict__ sos, const bf16* __restrict__ dec_tok,
        const int* __restrict__ num_chunks, const int* __restrict__ num_tokens,
        bf16* __restrict__ out) {
    int row = blockIdx.x;
    int p = row % 80;
    int bc = row / 80;
    int c = bc & 15, b = bc >> 4;
    int t = threadIdx.x;
    bf16* o = out + (long)row * 512;
    if (c < num_chunks[b]) {
        if (p <= c) {
            if (p == 0) {
                o[2 * t]     = f2b(sos[2 * t]);
                o[2 * t + 1] = f2b(sos[2 * t + 1]);
                return;
            }
            ((uint*)o)[t] = ((const uint*)(chunk_units + ((long)(b * 16 + p - 1)) * 512))[t];
            return;
        }
        int n = num_tokens[bc];
        if (p <= c + n) {
            ((uint*)o)[t] = ((const uint*)(dec_tok + ((long)bc * 64 + (p - c - 1)) * 512))[t];
            return;
        }
    }
    ((uint*)o)[t] = 0u;
}

// ---------------- Head gather ----------------
__global__ __launch_bounds__(256) void k_head_gather(const bf16* __restrict__ units,
        const int* __restrict__ num_chunks, const int* __restrict__ num_tokens,
        bf16* __restrict__ out) {
    int row = blockIdx.x;
    int t = row % 63;
    int bc = row / 63;
    int c = bc & 15, b = bc >> 4;
    bool valid = (c < num_chunks[b]) && (t < num_tokens[bc] - 1);
    uint* o = (uint*)(out + (long)row * 512);
    if (valid) {
        o[threadIdx.x] = ((const uint*)(units + ((long)bc * 80 + (c + 1 + t)) * 512))[threadIdx.x];
    } else {
        o[threadIdx.x] = 0u;
    }
}

// ---------------- Encoder driver (L=2 layers) ----------------
template<int S>
static void run_encoder(hipStream_t st, bf16* x, int nseq, const int* limits, int causal,
                        bf16* const* wts, const float* ln1, const float* ln2,
                        bf16* qkv, bf16* vt, bf16* att, bf16* proj, bf16* x2, bf16* h1) {
    constexpr int KT = S / 16;
    int R = nseq * S;
    int gy64 = (R + 63) / 64, gy32 = (R + 31) / 32;
    for (int l = 0; l < 2; ++l) {
        k_gemm_mfma<64, 64, 0, 0, 1, 1><<<dim3(24, gy64), 256, 0, st>>>(x, wts[l * 4 + 0], nullptr, qkv, R, 1536, 512, vt, S);
        k_attn_mfma<S><<<dim3(nseq * 8 * KT), 64, 0, st>>>(qkv, vt, att, limits, causal);
        k_gemm_mfma<32, 64, 0, 0, 1><<<dim3(8, gy32), 256, 0, st>>>(att, wts[l * 4 + 1], nullptr, proj, R, 512, 512, nullptr, 0);
        k_add_ln<<<dim3(R), 256, 0, st>>>(x, proj, ln1 + (long)l * 1024, x2);
        k_gemm_mfma<64, 64, 1, 0, 1><<<dim3(32, gy64), 256, 0, st>>>(x2, wts[l * 4 + 2], nullptr, h1, R, 2048, 512, nullptr, 0);
        k_gemm_mfma<32, 64, 0, 0, 1><<<dim3(8, gy32), 256, 0, st>>>(h1, wts[l * 4 + 3], nullptr, proj, R, 512, 2048, nullptr, 0);
        k_add_ln<<<dim3(R), 256, 0, st>>>(x2, proj, ln2 + (long)l * 1024, x);
    }
}

extern "C" void kernel_launch(void* const* d_in, const int* in_sizes, int n_in,
                              void* d_out, int out_size, void* d_ws, size_t ws_size,
                              hipStream_t stream) {
    (void)in_sizes; (void)n_in; (void)out_size; (void)ws_size;
    const int*   token_ids    = (const int*)d_in[0];
    const int*   num_chunks   = (const int*)d_in[1];
    const int*   num_tokens   = (const int*)d_in[2];
    const float* tok_emb      = (const float*)d_in[3];
    const float* tok_emb_ln   = (const float*)d_in[4];
    const float* chunk_pos    = (const float*)d_in[5];
    const float* chunk_emb_ln = (const float*)d_in[6];
    const float* sos          = (const float*)d_in[7];
    const float* dec_emb      = (const float*)d_in[8];
    const float* dec_emb_ln   = (const float*)d_in[9];
    const float* cls_dense    = (const float*)d_in[10];
    const float* cls_ln       = (const float*)d_in[11];
    const float* cls_proj     = (const float*)d_in[12];
    const float* cls_b        = (const float*)d_in[13];
    const float* w_in[3][4] = {
        {(const float*)d_in[14], (const float*)d_in[15], (const float*)d_in[17], (const float*)d_in[18]},
        {(const float*)d_in[20], (const float*)d_in[21], (const float*)d_in[23], (const float*)d_in[24]},
        {(const float*)d_in[26], (const float*)d_in[27], (const float*)d_in[29], (const float*)d_in[30]},
    };
    const float* ln_in[3][2] = {
        {(const float*)d_in[16], (const float*)d_in[19]},
        {(const float*)d_in[22], (const float*)d_in[25]},
        {(const float*)d_in[28], (const float*)d_in[31]},
    };

    char* p = (char*)d_ws;
    auto carve_b = [&](size_t elems) {
        bf16* r = (bf16*)p;
        p += ((elems * 2 + 255) / 256) * 256;
        return r;
    };
    bf16* x       = carve_b((size_t)2560 * 512);
    bf16* qkv     = carve_b((size_t)2560 * 1536);
    bf16* vt      = carve_b((size_t)32 * 8 * 64 * 96);
    bf16* att     = carve_b((size_t)2560 * 512);
    bf16* proj    = carve_b((size_t)2560 * 512);
    bf16* x2      = carve_b((size_t)2560 * 512);
    bf16* h1      = carve_b((size_t)2560 * 2048);
    bf16* chunk_x = carve_b((size_t)64 * 512);
    bf16* dec_tok = carve_b((size_t)2048 * 512);
    bf16* unitsre = carve_b((size_t)2048 * 512);
    bf16* hbuf    = carve_b((size_t)2048 * 512);
    bf16* ybuf    = carve_b((size_t)2048 * 512);

    TAll ta;
    int nm = 0, tiles = 0;
    auto push = [&](const float* src, int K, int N) -> bf16* {
        bf16* dst = carve_b((size_t)K * N);
        ta.src[nm] = src; ta.dst[nm] = dst; ta.K[nm] = K; ta.N[nm] = N;
        ta.ofs[nm] = tiles;
        tiles += (K / 32) * (N / 32);
        ++nm;
        return dst;
    };
    static const int KN[4][2] = {{512, 1536}, {512, 512}, {512, 2048}, {2048, 512}};
    bf16* wt[3][8];
    for (int tf = 0; tf < 3; ++tf)
        for (int l = 0; l < 2; ++l)
            for (int m = 0; m < 4; ++m) {
                int K = KN[m][0], N = KN[m][1];
                wt[tf][l * 4 + m] = push(w_in[tf][m] + (long)l * K * N, K, N);
            }
    bf16* wt_dense = push(cls_dense, 512, 512);
    bf16* wt_proj  = push(cls_proj, 512, 32000);
    ta.ofs[nm] = tiles;   // nm == NMAT == 26

    k_transpose<<<dim3(tiles), 256, 0, stream>>>(ta);

    // embeddings (tok + dec merged)
    k_embed_ln2<<<4096, 256, 0, stream>>>(token_ids, tok_emb, tok_emb_ln, dec_emb, dec_emb_ln, x, dec_tok);

    // 1) token encoder (32 seq x 64)
    run_encoder<64>(stream, x, 32, num_tokens, 0, wt[0], ln_in[0][0], ln_in[0][1],
                    qkv, vt, att, proj, x2, h1);
    // 2) chunk encoder (2 seq x 16)
    k_chunk_ln<<<32, 256, 0, stream>>>(x, chunk_pos, chunk_emb_ln, chunk_x);
    run_encoder<16>(stream, chunk_x, 2, num_chunks, 1, wt[1], ln_in[1][0], ln_in[1][1],
                    qkv, vt, att, proj, x2, h1);
    // 3) decoder (32 seq x 80)
    k_dec_in<<<2560, 256, 0, stream>>>(chunk_x, sos, dec_tok, num_chunks, num_tokens, x);
    run_encoder<80>(stream, x, 32, nullptr, 1, wt[2], ln_in[2][0], ln_in[2][1],
                    qkv, vt, att, proj, x2, h1);
    // 4) head
    k_head_gather<<<2016, 256, 0, stream>>>(x, num_chunks, num_tokens, unitsre);
    k_gemm_mfma<32, 64, 1, 0, 1><<<dim3(8, 63), 256, 0, stream>>>(unitsre, wt_dense, nullptr, hbuf, 2016, 512, 512, nullptr, 0);
    k_add_ln<<<2016, 256, 0, stream>>>(hbuf, nullptr, cls_ln, ybuf);
    // logits: 128x128, XCD co-location, LDS-transposed coalesced f32 epilogue
    k_gemm_mfma<128, 128, 0, 1, 0, 0, 1, 1><<<dim3(16, 256), 256, 0, stream>>>(ybuf, wt_proj, cls_b, d_out, 2016, 32000, 512, nullptr, 0);
}